// Round 2
// baseline (918.027 us; speedup 1.0000x reference)
//
#include <hip/hip_runtime.h>

#define SEQ 4096
#define NT  256
#define NA  64
#define K2_T 256          // steps per output chunk
#define K2_K 128          // truncated warm-up window
#define K2_C (SEQ / K2_T) // 16 chunks
#define LOG2E 1.4426950408889634f

__device__ __forceinline__ float rdlane(float v, int l) {
    return __int_as_float(__builtin_amdgcn_readlane(__float_as_int(v), l));
}

// ---------------------------------------------------------------------------
// Kernel 1: per-algo scalar chain. One wave (64 lanes) per algo.
// Lane L maintains the windowed partial for its next production step T
// (T ≡ L mod 64):  P = sum_{v=T-64..T-1} mem^(T-1-v) * g_v * tm[lx[v]][lx[T]]
// (exact for T<=64, window truncation ~mem^64 <= ~1e-8 otherwise).
// Each step the owner's P completes -> broadcast -> sigmoid -> next g.
// g_t = eff + sig_{t-1}[lx[t]]*boost = A + B*q,  q = 1/(e^{res/d}+1).
// ---------------------------------------------------------------------------
__global__ __launch_bounds__(64) void k_chain(
    const int* __restrict__ lx, const float* __restrict__ tm,
    const float* __restrict__ diff, const float* __restrict__ eff_p,
    const float* __restrict__ mem_p, const float* __restrict__ boost_p,
    float* __restrict__ gbuf)
{
    __shared__ int   s_lx[SEQ];
    __shared__ float s_k[NT];
    const int lane = threadIdx.x;
    const int a = blockIdx.x;
    for (int i = lane; i < SEQ; i += 64) s_lx[i] = lx[i];
    for (int i = lane; i < NT; i += 64) s_k[i] = LOG2E / diff[i];
    __syncthreads();

    const float eff   = eff_p[a];
    const float mem   = mem_p[a];
    const float boost = boost_p[a];
    const float A = eff + boost;
    const float B = -2.0f * boost;
    const float rmem = 1.0f / mem;
    float mem63 = 1.0f;
    for (int i = 0; i < 63; ++i) mem63 *= mem;

    int T = (lane == 0) ? 64 : lane;   // first production step for this lane
    float w = 1.0f;                    // w = mem^(T-1-u)
    for (int i = 0; i < T - 1; ++i) w *= mem;
    float P = 0.0f;
    int   ct = s_lx[T];
    float kt = s_k[ct];                // log2(e)/d[lx[T]] for the eventual sigmoid
    float g = eff;                     // g_0 (sig_{-1} = 0)
    if (lane == 0) gbuf[a * SEQ] = g;

    // register prefetch pipeline, depth 8 (addresses fully static given lx)
    float pf[8];
#pragma unroll
    for (int j = 0; j < 8; ++j) {
        int u = j;
        int tgt = u + 1 + ((lane - u - 1) & 63);
        if (tgt > SEQ - 1) tgt = SEQ - 1;
        pf[j] = tm[s_lx[u] * NT + s_lx[tgt]];
    }

    for (int u0 = 0; u0 < SEQ; u0 += 8) {
#pragma unroll
        for (int j = 0; j < 8; ++j) {
            const int u = u0 + j;
            const float tmv = pf[j];
            P = fmaf(w * g, tmv, P);               // adds v=u term; owner's P completes
            const int o = (u + 1) & 63;            // owner lane (uniform)
            const float pb  = rdlane(P, o);        // res_u[lx[u+1]] (windowed)
            const float kto = rdlane(kt, o);
            const float q = __builtin_amdgcn_rcpf(
                                __builtin_amdgcn_exp2f(pb * kto) + 1.0f);
            g = fmaf(B, q, A);                     // g_{u+1}, uniform on all lanes
            if (lane == o) {
                if (u + 1 < SEQ) gbuf[a * SEQ + u + 1] = g;
                P = 0.0f;
                w = mem63;
                T += 64;
                int Tc = (T > SEQ - 1) ? (SEQ - 1) : T;
                ct = s_lx[Tc];
                kt = s_k[ct];
            } else {
                w *= rmem;
            }
            // prefetch tm value for step u+8
            int un = u + 8;
            int ur = (un > SEQ - 1) ? (SEQ - 1) : un;
            int tgt = un + 1 + ((lane - un - 1) & 63);
            if (tgt > SEQ - 1) tgt = SEQ - 1;
            pf[j] = tm[s_lx[ur] * NT + s_lx[tgt]];
        }
    }
}

// ---------------------------------------------------------------------------
// Kernel 2: given g[a][t], regenerate res/sig for all (a,c,t) in parallel.
// Block = 1 wave = 64 columns; grid = algo x 4 col-groups x 16 chunks.
// 128-step truncated warm-up (exact for chunk 0; mem^128 ~ 0 otherwise).
// 64x65 LDS tile transpose so HBM stores are 256B-contiguous along t.
// ---------------------------------------------------------------------------
__global__ __launch_bounds__(64) void k_out(
    const int* __restrict__ lx, const float* __restrict__ tm,
    const float* __restrict__ diff, const float* __restrict__ mem_p,
    const float* __restrict__ gbuf, float* __restrict__ out)
{
    __shared__ int   s_lx[K2_K + K2_T];
    __shared__ float s_g[K2_K + K2_T];
    __shared__ float s_tile[64 * 65];

    const int lane = threadIdx.x;
    const int b = blockIdx.x;
    const int a     = b >> 6;          // /64
    const int cg    = (b >> 4) & 3;    // col group (4 of 64 cols each)
    const int chunk = b & 15;          // 16 chunks of 256 steps
    const int t0 = chunk * K2_T;
    const int vstart = (chunk == 0) ? 0 : t0 - K2_K;
    const int n = t0 + K2_T - vstart;
    for (int i = lane; i < n; i += 64) {
        s_lx[i] = lx[vstart + i];
        s_g[i]  = gbuf[a * SEQ + vstart + i];
    }
    __syncthreads();

    const int c = (cg << 6) + lane;
    const float memv = mem_p[a];
    const float kc = LOG2E / diff[c];
    float res = 0.0f;
    const int wlen = t0 - vstart;
#pragma unroll 4
    for (int i = 0; i < wlen; ++i) {
        float tmv = tm[s_lx[i] * NT + c];
        res = fmaf(memv, res, tmv * s_g[i]);
    }

    const long rowbase = (long)(a * NT + (cg << 6)) * (SEQ + 1);
    for (int jb = 0; jb < K2_T; jb += 64) {
#pragma unroll 4
        for (int j2 = 0; j2 < 64; ++j2) {
            int i = wlen + jb + j2;
            float tmv = tm[s_lx[i] * NT + c];
            res = fmaf(memv, res, tmv * s_g[i]);
            float q = __builtin_amdgcn_rcpf(
                          __builtin_amdgcn_exp2f(res * kc) + 1.0f);
            s_tile[j2 * 65 + lane] = fmaf(-2.0f, q, 1.0f);
        }
        __syncthreads();
        const int tbase = t0 + jb + 1;
#pragma unroll 4
        for (int r = 0; r < 64; ++r) {
            out[rowbase + (long)r * (SEQ + 1) + tbase + lane] = s_tile[lane * 65 + r];
        }
        __syncthreads();
    }
    if (chunk == 0) out[rowbase + (long)lane * (SEQ + 1)] = 0.0f;
}

extern "C" void kernel_launch(void* const* d_in, const int* in_sizes, int n_in,
                              void* d_out, int out_size, void* d_ws, size_t ws_size,
                              hipStream_t stream)
{
    const int*   lx    = (const int*)d_in[0];
    const float* tm    = (const float*)d_in[1];
    const float* diff  = (const float*)d_in[2];
    const float* eff   = (const float*)d_in[3];
    const float* memp  = (const float*)d_in[4];
    const float* boost = (const float*)d_in[5];
    float* gbuf = (float*)d_ws;                       // 64*4096*4 = 1 MB
    float* out  = (float*)d_out;

    k_chain<<<NA, 64, 0, stream>>>(lx, tm, diff, eff, memp, boost, gbuf);
    k_out<<<NA * 4 * K2_C, 64, 0, stream>>>(lx, tm, diff, memp, gbuf, out);
}

// Round 3
// 768.187 us; speedup vs baseline: 1.1951x; 1.1951x over previous
//
#include <hip/hip_runtime.h>

#define SEQ 4096
#define NT  256
#define NA  64
#define NCKPT 16          // res checkpoints, every 256 steps
#define LOG2E 1.4426950408889634f

__device__ __forceinline__ float rdlane(float v, int l) {
    return __int_as_float(__builtin_amdgcn_readlane(__float_as_int(v), l));
}

// ---------------------------------------------------------------------------
// Kernel 1: exact full-state chain. One wave per algo; lane owns columns
// 4L..4L+3 of res[256].  Per step u:
//   res_u[c] = mem*res_{u-1}[c] + tm[lx[u]][c] * g_u        (coalesced row load)
//   g_{u+1}  = A + B * rcp(exp2(k*(mem*res_{u-1}[col] + tv*g_u)) + 1)
// where col = lx[u+1], tv = tm[lx[u]][col]; tv*k and mem*k are precomputed
// per-step so the serial chain is fma -> exp2 -> add -> rcp -> fma.
// Also stores res checkpoints every 256 steps for k_out.
// ---------------------------------------------------------------------------
__global__ __launch_bounds__(64) void k_chain(
    const int* __restrict__ lx, const float* __restrict__ tm,
    const float* __restrict__ diff, const float* __restrict__ eff_p,
    const float* __restrict__ mem_p, const float* __restrict__ boost_p,
    float* __restrict__ gbuf, float* __restrict__ ckpt)
{
    __shared__ int   s_lx[SEQ + 8];
    __shared__ float s_tvk[SEQ + 8];   // tvk[t] = tm[lx[t-1]][lx[t]] * k[lx[t]]
    __shared__ float s_kmem[SEQ + 8];  // kmem[t] = mem * k[lx[t]]
    const int lane = threadIdx.x;
    const int a = blockIdx.x;

    for (int i = lane; i < SEQ; i += 64) s_lx[i] = lx[i];
    if (lane < 8) s_lx[SEQ + lane] = lx[SEQ - 1];
    __syncthreads();

    const float eff   = eff_p[a];
    const float mem   = mem_p[a];
    const float boost = boost_p[a];
    const float A = eff + boost;
    const float B = -2.0f * boost;

    // prologue: per-step uniform constants (gathers pipeline independently)
    for (int t = lane; t < SEQ; t += 64) {
        int c = s_lx[t];
        float k = LOG2E / diff[c];
        s_kmem[t] = mem * k;
        float tv = (t >= 1) ? tm[s_lx[t - 1] * NT + c] : 0.0f;
        s_tvk[t] = tv * k;
    }
    if (lane < 8) { s_kmem[SEQ + lane] = 0.0f; s_tvk[SEQ + lane] = 0.0f; }
    __syncthreads();

    float4 res = make_float4(0.0f, 0.0f, 0.0f, 0.0f);
    float g = eff;            // g_0  (sig_{-1} = 0)
    float gsave = g;

    // prefetch ring: tm row for step u, depth 8, coalesced float4 per lane
    float4 pf[8];
#pragma unroll
    for (int d = 0; d < 8; ++d)
        pf[d] = *(const float4*)(tm + s_lx[d] * NT + 4 * lane);

    for (int u0 = 0; u0 < SEQ; u0 += 8) {
#pragma unroll
        for (int j = 0; j < 8; ++j) {
            const int u = u0 + j;
            // capture g_u into lane (u&63)'s gsave
            gsave = (lane == (u & 63)) ? g : gsave;

            const int   coln  = s_lx[u + 1];
            const float tvkn  = s_tvk[u + 1];
            const float kmemn = s_kmem[u + 1];

            // probe res_{u-1}[coln] (pre-update) -> off-chain readlane
            const int o = coln >> 2, sub = coln & 3;
            float r01 = (sub & 1) ? res.y : res.x;
            float r23 = (sub & 1) ? res.w : res.z;
            float rsel = (sub & 2) ? r23 : r01;
            const float c1 = rdlane(rsel, o) * kmemn;

            // res update (parallel with the sigmoid chain)
            const float4 row = pf[j];
            res.x = fmaf(g, row.x, mem * res.x);
            res.y = fmaf(g, row.y, mem * res.y);
            res.z = fmaf(g, row.z, mem * res.z);
            res.w = fmaf(g, row.w, mem * res.w);

            // serial chain: g_{u+1}
            const float pb = fmaf(tvkn, g, c1);
            const float q  = __builtin_amdgcn_rcpf(
                                 __builtin_amdgcn_exp2f(pb) + 1.0f);
            g = fmaf(B, q, A);

            // batched g store: one coalesced store per 64 steps
            if ((u & 63) == 63) gbuf[a * SEQ + (u & ~63) + lane] = gsave;
            // res checkpoint every 256 steps (res after step u)
            if ((u & 255) == 255)
                *(float4*)(ckpt + (a * NCKPT + (u >> 8)) * NT + 4 * lane) = res;

            // prefetch tm row for step u+8
            int up = u + 8; if (up >= SEQ) up = SEQ - 1;
            pf[j] = *(const float4*)(tm + s_lx[up] * NT + 4 * lane);
        }
    }
}

// ---------------------------------------------------------------------------
// Kernel 2: regenerate sig for all (a, col, t) from g + checkpoints.
// Block = 1 wave = 64 columns; grid = algo x 4 col-groups x 16 chunks of 256.
// No warm-up: res initialized from the exact checkpoint.
// 64x65 LDS tile transpose so HBM stores are contiguous along t.
// ---------------------------------------------------------------------------
__global__ __launch_bounds__(64) void k_out(
    const int* __restrict__ lx, const float* __restrict__ tm,
    const float* __restrict__ diff, const float* __restrict__ mem_p,
    const float* __restrict__ gbuf, const float* __restrict__ ckpt,
    float* __restrict__ out)
{
    __shared__ int   s_lx[256];
    __shared__ float s_g[256];
    __shared__ float s_tile[64 * 65];

    const int lane = threadIdx.x;
    const int b = blockIdx.x;
    const int a     = b >> 6;
    const int cg    = (b >> 4) & 3;
    const int chunk = b & 15;
    const int t0 = chunk << 8;

    for (int i = lane; i < 256; i += 64) {
        s_lx[i] = lx[t0 + i];
        s_g[i]  = gbuf[a * SEQ + t0 + i];
    }
    __syncthreads();

    const int c = (cg << 6) + lane;
    const float memv = mem_p[a];
    const float kc = LOG2E / diff[c];
    float res = (chunk == 0) ? 0.0f
                             : ckpt[(a * NCKPT + chunk - 1) * NT + c];

    // prefetch ring depth 8 for tm[lx[t0+i]][c]
    float pf[8];
#pragma unroll
    for (int d = 0; d < 8; ++d) pf[d] = tm[s_lx[d] * NT + c];

    const long rowbase = (long)(a * NT + (cg << 6)) * (SEQ + 1);
    for (int jb = 0; jb < 256; jb += 64) {
#pragma unroll 8
        for (int j2 = 0; j2 < 64; ++j2) {
            const int i = jb + j2;
            const float tmv = pf[i & 7];
            res = fmaf(memv, res, tmv * s_g[i]);
            const float q = __builtin_amdgcn_rcpf(
                                __builtin_amdgcn_exp2f(res * kc) + 1.0f);
            s_tile[j2 * 65 + lane] = fmaf(-2.0f, q, 1.0f);
            int in8 = i + 8; if (in8 > 255) in8 = 255;
            pf[i & 7] = tm[s_lx[in8] * NT + c];
        }
        __syncthreads();
        const int tbase = t0 + jb + 1;
#pragma unroll 8
        for (int r = 0; r < 64; ++r) {
            out[rowbase + (long)r * (SEQ + 1) + tbase + lane] =
                s_tile[lane * 65 + r];
        }
        __syncthreads();
    }
    if (chunk == 0) out[rowbase + (long)lane * (SEQ + 1)] = 0.0f;
}

extern "C" void kernel_launch(void* const* d_in, const int* in_sizes, int n_in,
                              void* d_out, int out_size, void* d_ws, size_t ws_size,
                              hipStream_t stream)
{
    const int*   lx    = (const int*)d_in[0];
    const float* tm    = (const float*)d_in[1];
    const float* diff  = (const float*)d_in[2];
    const float* eff   = (const float*)d_in[3];
    const float* memp  = (const float*)d_in[4];
    const float* boost = (const float*)d_in[5];
    float* gbuf = (float*)d_ws;                          // 64*4096*4 = 1 MB
    float* ckpt = gbuf + NA * SEQ;                       // 64*16*256*4 = 1 MB
    float* out  = (float*)d_out;

    k_chain<<<NA, 64, 0, stream>>>(lx, tm, diff, eff, memp, boost, gbuf, ckpt);
    k_out<<<NA * 4 * NCKPT, 64, 0, stream>>>(lx, tm, diff, memp, gbuf, ckpt, out);
}